// Round 1
// baseline (5437.548 us; speedup 1.0000x reference)
//
#include <hip/hip_runtime.h>
#include <hip/hip_fp16.h>

typedef _Float16 half8 __attribute__((ext_vector_type(8)));
typedef float floatx4 __attribute__((ext_vector_type(4)));

#define PLANE 65536              // 16*16*256 fp16 elems per image
#define PK_ELEMS 589824          // 9*8*16*64*8 per layer

// ---------------- weight repack: fp32 -> fp16 MFMA B-fragment layout ----------------
// pack[layer][tap][ks][nt][lane][j] = W[co = nt*16+(lane&15)][ci = ks*32+(lane>>4)*8+j][tap]
// layer 3 = convT effective weight: wt[ci][co][2-ky][2-kx]
__global__ void repack_kernel(const float* __restrict__ w2, const float* __restrict__ w3,
                              const float* __restrict__ w4, const float* __restrict__ wt,
                              _Float16* __restrict__ pk) {
    int t = blockIdx.x * 256 + threadIdx.x;     // 294912 total
    int l = t & 63;
    int idx = t >> 6;
    int nt = idx & 15; idx >>= 4;
    int ks = idx & 7;  idx >>= 3;               // idx in [0,36)
    int tap = idx % 9;
    int layer = idx / 9;
    int co = nt * 16 + (l & 15);
    int ci0 = ks * 32 + (l >> 4) * 8;
    const float* w = (layer == 0) ? w2 : (layer == 1) ? w3 : (layer == 2) ? w4 : wt;
    _Float16* dst = pk + (size_t)layer * PK_ELEMS + (((size_t)(tap * 8 + ks) * 16 + nt) * 64 + l) * 8;
    if (layer < 3) {
        for (int j = 0; j < 8; ++j)
            dst[j] = (_Float16)w[(co * 256 + (ci0 + j)) * 9 + tap];
    } else {
        int ky = tap / 3, kx = tap % 3;
        for (int j = 0; j < 8; ++j)
            dst[j] = (_Float16)w[((ci0 + j) * 256 + co) * 9 + (2 - ky) * 3 + (2 - kx)];
    }
}

// ---------------- conv1: 3->256, direct fp32, writes padded swizzled fp16 act ----------------
__global__ __launch_bounds__(1024) void conv1_kernel(const float* __restrict__ x,
                                                     const float* __restrict__ w1,
                                                     const float* __restrict__ b1,
                                                     _Float16* __restrict__ act) {
    __shared__ float inl[3][16][16];
    __shared__ float lw[256 * 27];
    int n = blockIdx.x, tid = threadIdx.x;
    if (tid < 768) ((float*)inl)[tid] = 0.f;
    __syncthreads();
    for (int i = tid; i < 3 * 196; i += 1024) {
        int ci = i / 196, r = i % 196, y = r / 14, xx = r % 14;
        inl[ci][y + 1][xx + 1] = x[(size_t)n * 588 + i];
    }
    for (int i = tid; i < 256 * 27; i += 1024) lw[i] = w1[i];
    __syncthreads();
    int p = tid >> 2, q = tid & 3;
    int py = p >> 4, px = p & 15;
    _Float16* ga = act + (size_t)n * PLANE + p * 256;
    int sw = (p & 7) << 3;
    if (py == 0 || py == 15 || px == 0 || px == 15) {
        for (int co = q * 64; co < q * 64 + 64; ++co) ga[co ^ sw] = (_Float16)0.f;
    } else {
        float vin[27];
        #pragma unroll
        for (int ci = 0; ci < 3; ++ci)
            #pragma unroll
            for (int ky = 0; ky < 3; ++ky)
                #pragma unroll
                for (int kx = 0; kx < 3; ++kx)
                    vin[ci * 9 + ky * 3 + kx] = inl[ci][py - 1 + ky][px - 1 + kx];
        for (int co = q * 64; co < q * 64 + 64; ++co) {
            float acc = b1[co];
            const float* wp = &lw[co * 27];
            #pragma unroll
            for (int k = 0; k < 27; ++k) acc += vin[k] * wp[k];
            ga[co ^ sw] = (_Float16)fmaxf(acc, 0.f);
        }
    }
}

// ---------------- conv 3x3 256->256 + ReLU, MFMA implicit GEMM, in-place ----------------
__global__ __launch_bounds__(1024) void conv3x3_kernel(_Float16* __restrict__ act,
                                                       const _Float16* __restrict__ pk,
                                                       const float* __restrict__ bias) {
    __shared__ _Float16 lds[PLANE];   // 128 KB
    int n = blockIdx.x, tid = threadIdx.x;
    _Float16* ga = act + (size_t)n * PLANE;
    #pragma unroll
    for (int i = 0; i < 8; ++i)
        *(uint4*)(lds + (i * 1024 + tid) * 8) = *(const uint4*)(ga + (i * 1024 + tid) * 8);
    __syncthreads();

    int lane = tid & 63, wid = tid >> 6;
    int wm = wid >> 2, wn = wid & 3;
    int r = lane & 15, kg = lane >> 4;
    int pp[4];
    #pragma unroll
    for (int i = 0; i < 4; ++i) {
        int mt = wm + i * 4, m = mt * 16 + r;
        if (mt < 13 && m < 196) { int y = m / 14, xx = m - y * 14; pp[i] = (y + 1) * 16 + xx + 1; }
        else pp[i] = 17;
    }
    float bia[4];
    #pragma unroll
    for (int ni = 0; ni < 4; ++ni) bia[ni] = bias[(wn * 4 + ni) * 16 + (lane & 15)];

    floatx4 acc[4][4] = {};
    for (int tap = 0; tap < 9; ++tap) {
        int dy = tap / 3 - 1, dx = tap % 3 - 1;
        int ip[4];
        #pragma unroll
        for (int i = 0; i < 4; ++i) ip[i] = pp[i] + dy * 16 + dx;
        const _Float16* pkt = pk + (size_t)tap * (8 * 16 * 64 * 8);
        #pragma unroll
        for (int ks = 0; ks < 8; ++ks) {
            half8 a[4], b[4];
            #pragma unroll
            for (int i = 0; i < 4; ++i) {
                int chunk = (ks * 4 + kg) ^ (ip[i] & 7);
                a[i] = *(const half8*)(lds + ip[i] * 256 + chunk * 8);
            }
            #pragma unroll
            for (int ni = 0; ni < 4; ++ni)
                b[ni] = *(const half8*)(pkt + (((ks * 16) + wn * 4 + ni) * 64 + lane) * 8);
            #pragma unroll
            for (int i = 0; i < 4; ++i)
                #pragma unroll
                for (int ni = 0; ni < 4; ++ni)
                    acc[i][ni] = __builtin_amdgcn_mfma_f32_16x16x32_f16(a[i], b[ni], acc[i][ni], 0, 0, 0);
        }
    }
    #pragma unroll
    for (int i = 0; i < 4; ++i) {
        int mt = wm + i * 4;
        if (mt >= 13) continue;
        #pragma unroll
        for (int ni = 0; ni < 4; ++ni) {
            int co = (wn * 4 + ni) * 16 + (lane & 15);
            #pragma unroll
            for (int reg = 0; reg < 4; ++reg) {
                int m = mt * 16 + kg * 4 + reg;
                if (m >= 196) continue;
                int y = m / 14, xx = m - y * 14;
                int ppix = (y + 1) * 16 + xx + 1;
                float v = fmaxf(acc[i][ni][reg] + bia[ni], 0.f);
                ga[ppix * 256 + (co ^ ((ppix & 7) << 3))] = (_Float16)v;
            }
        }
    }
}

// ---------------- convT (stride2) + ReLU + 1x1 conv + sigmoid, fused ----------------
__global__ __launch_bounds__(1024) void convt_kernel(const _Float16* __restrict__ act,
                                                     const _Float16* __restrict__ pkT,
                                                     const float* __restrict__ bt,
                                                     const float* __restrict__ w5,
                                                     const float* __restrict__ b5,
                                                     float* __restrict__ out) {
    __shared__ _Float16 lds[PLANE];   // 128 KB
    __shared__ float o3[2352];        // 9.2 KB: [pix][c]
    int n = blockIdx.x, tid = threadIdx.x;
    const _Float16* ga = act + (size_t)n * PLANE;
    #pragma unroll
    for (int i = 0; i < 8; ++i)
        *(uint4*)(lds + (i * 1024 + tid) * 8) = *(const uint4*)(ga + (i * 1024 + tid) * 8);
    for (int i = tid; i < 2352; i += 1024) o3[i] = b5[i % 3];
    __syncthreads();

    int lane = tid & 63, wid = tid >> 6;
    int wm = wid >> 2, wn = wid & 3;
    int r = lane & 15, kg = lane >> 4;
    int pp[4];
    #pragma unroll
    for (int i = 0; i < 4; ++i) {
        int mt = wm + i * 4, m = mt * 16 + r;
        if (mt < 13 && m < 196) { int y = m / 14, xx = m - y * 14; pp[i] = (y + 1) * 16 + xx + 1; }
        else pp[i] = 17;
    }
    float bta[4], w5a[4][3];
    #pragma unroll
    for (int ni = 0; ni < 4; ++ni) {
        int co = (wn * 4 + ni) * 16 + (lane & 15);
        bta[ni] = bt[co];
        #pragma unroll
        for (int c = 0; c < 3; ++c) w5a[ni][c] = w5[c * 256 + co];
    }

    const int ntaps[4] = {1, 2, 2, 4};
    const int taps[4][4] = {{4, 0, 0, 0}, {3, 5, 0, 0}, {1, 7, 0, 0}, {0, 2, 6, 8}};
    const int dys[4][4]  = {{0, 0, 0, 0}, {0, 0, 0, 0}, {0, 1, 0, 0}, {0, 0, 1, 1}};
    const int dxs[4][4]  = {{0, 0, 0, 0}, {0, 1, 0, 0}, {0, 0, 0, 0}, {0, 1, 0, 1}};

    for (int cls = 0; cls < 4; ++cls) {
        int ry = cls >> 1, rx = cls & 1;
        floatx4 acc[4][4] = {};
        for (int tt = 0; tt < ntaps[cls]; ++tt) {
            int tap = taps[cls][tt];
            int doff = dys[cls][tt] * 16 + dxs[cls][tt];
            const _Float16* pkt = pkT + (size_t)tap * (8 * 16 * 64 * 8);
            #pragma unroll
            for (int ks = 0; ks < 8; ++ks) {
                half8 a[4], b[4];
                #pragma unroll
                for (int i = 0; i < 4; ++i) {
                    int ipx = pp[i] + doff;
                    int chunk = (ks * 4 + kg) ^ (ipx & 7);
                    a[i] = *(const half8*)(lds + ipx * 256 + chunk * 8);
                }
                #pragma unroll
                for (int ni = 0; ni < 4; ++ni)
                    b[ni] = *(const half8*)(pkt + (((ks * 16) + wn * 4 + ni) * 64 + lane) * 8);
                #pragma unroll
                for (int i = 0; i < 4; ++i)
                    #pragma unroll
                    for (int ni = 0; ni < 4; ++ni)
                        acc[i][ni] = __builtin_amdgcn_mfma_f32_16x16x32_f16(a[i], b[ni], acc[i][ni], 0, 0, 0);
            }
        }
        // ReLU + 1x1 conv partial accumulation into o3
        #pragma unroll
        for (int i = 0; i < 4; ++i) {
            int mt = wm + i * 4;
            if (mt >= 13) continue;
            #pragma unroll
            for (int ni = 0; ni < 4; ++ni) {
                #pragma unroll
                for (int reg = 0; reg < 4; ++reg) {
                    int m = mt * 16 + kg * 4 + reg;
                    if (m >= 196) continue;
                    int y = m / 14, xx = m - y * 14;
                    int pix = (2 * y + ry) * 28 + (2 * xx + rx);
                    float v = fmaxf(acc[i][ni][reg] + bta[ni], 0.f);
                    #pragma unroll
                    for (int c = 0; c < 3; ++c)
                        atomicAdd(&o3[pix * 3 + c], v * w5a[ni][c]);
                }
            }
        }
    }
    __syncthreads();
    size_t ob = (size_t)n * 2352;
    for (int i = tid; i < 2352; i += 1024) {
        int pix = i / 3, c = i % 3;
        float v = o3[i];
        out[ob + (size_t)c * 784 + pix] = 1.f / (1.f + __expf(-v));
    }
}

extern "C" void kernel_launch(void* const* d_in, const int* in_sizes, int n_in,
                              void* d_out, int out_size, void* d_ws, size_t ws_size,
                              hipStream_t stream) {
    const float* x  = (const float*)d_in[0];
    const float* w1 = (const float*)d_in[1];
    const float* b1 = (const float*)d_in[2];
    const float* w2 = (const float*)d_in[3];
    const float* b2 = (const float*)d_in[4];
    const float* w3 = (const float*)d_in[5];
    const float* b3 = (const float*)d_in[6];
    const float* w4 = (const float*)d_in[7];
    const float* b4 = (const float*)d_in[8];
    const float* wt = (const float*)d_in[9];
    const float* bt = (const float*)d_in[10];
    const float* w5 = (const float*)d_in[11];
    const float* b5 = (const float*)d_in[12];

    size_t need = ((size_t)1024 * PLANE + 4 * (size_t)PK_ELEMS) * sizeof(_Float16);
    if (ws_size < need) return;  // workspace too small — cannot run

    _Float16* act = (_Float16*)d_ws;
    _Float16* pk  = act + (size_t)1024 * PLANE;

    repack_kernel<<<1152, 256, 0, stream>>>(w2, w3, w4, wt, pk);
    conv1_kernel<<<1024, 1024, 0, stream>>>(x, w1, b1, act);
    conv3x3_kernel<<<1024, 1024, 0, stream>>>(act, pk + 0 * (size_t)PK_ELEMS, b2);
    conv3x3_kernel<<<1024, 1024, 0, stream>>>(act, pk + 1 * (size_t)PK_ELEMS, b3);
    conv3x3_kernel<<<1024, 1024, 0, stream>>>(act, pk + 2 * (size_t)PK_ELEMS, b4);
    convt_kernel<<<1024, 1024, 0, stream>>>(act, pk + 3 * (size_t)PK_ELEMS, bt, w5, b5, (float*)d_out);
}

// Round 2
// 1647.344 us; speedup vs baseline: 3.3008x; 3.3008x over previous
//
#include <hip/hip_runtime.h>
#include <hip/hip_fp16.h>

typedef _Float16 half8 __attribute__((ext_vector_type(8)));
typedef float floatx4 __attribute__((ext_vector_type(4)));

#define PLANE 65536              // 16*16*256 fp16 elems per image
#define PK_ELEMS 589824          // 9*8*16*64*8 per layer

// ---------------- weight repack: fp32 -> fp16 MFMA B-fragment layout ----------------
// pack[layer][tap][ks][nt][lane][j] = W[co = nt*16+(lane&15)][ci = ks*32+(lane>>4)*8+j][tap]
// layer 3 = convT effective weight: wt[ci][co][2-ky][2-kx]
__global__ void repack_kernel(const float* __restrict__ w2, const float* __restrict__ w3,
                              const float* __restrict__ w4, const float* __restrict__ wt,
                              _Float16* __restrict__ pk) {
    int t = blockIdx.x * 256 + threadIdx.x;     // 294912 total
    int l = t & 63;
    int idx = t >> 6;
    int nt = idx & 15; idx >>= 4;
    int ks = idx & 7;  idx >>= 3;               // idx in [0,36)
    int tap = idx % 9;
    int layer = idx / 9;
    int co = nt * 16 + (l & 15);
    int ci0 = ks * 32 + (l >> 4) * 8;
    const float* w = (layer == 0) ? w2 : (layer == 1) ? w3 : (layer == 2) ? w4 : wt;
    _Float16* dst = pk + (size_t)layer * PK_ELEMS + (((size_t)(tap * 8 + ks) * 16 + nt) * 64 + l) * 8;
    if (layer < 3) {
        for (int j = 0; j < 8; ++j)
            dst[j] = (_Float16)w[(co * 256 + (ci0 + j)) * 9 + tap];
    } else {
        int ky = tap / 3, kx = tap % 3;
        for (int j = 0; j < 8; ++j)
            dst[j] = (_Float16)w[((ci0 + j) * 256 + co) * 9 + (2 - ky) * 3 + (2 - kx)];
    }
}

// ---------------- conv1: 3->256, direct fp32, writes padded swizzled fp16 act ----------------
__global__ __launch_bounds__(1024, 4) void conv1_kernel(const float* __restrict__ x,
                                                        const float* __restrict__ w1,
                                                        const float* __restrict__ b1,
                                                        _Float16* __restrict__ act) {
    __shared__ float inl[3][16][16];
    __shared__ float lw[256 * 27];
    int n = blockIdx.x, tid = threadIdx.x;
    if (tid < 768) ((float*)inl)[tid] = 0.f;
    __syncthreads();
    for (int i = tid; i < 3 * 196; i += 1024) {
        int ci = i / 196, r = i % 196, y = r / 14, xx = r % 14;
        inl[ci][y + 1][xx + 1] = x[(size_t)n * 588 + i];
    }
    for (int i = tid; i < 256 * 27; i += 1024) lw[i] = w1[i];
    __syncthreads();
    int p = tid >> 2, q = tid & 3;
    int py = p >> 4, px = p & 15;
    _Float16* ga = act + (size_t)n * PLANE + p * 256;
    int sw = (p & 7) << 3;
    if (py == 0 || py == 15 || px == 0 || px == 15) {
        for (int co = q * 64; co < q * 64 + 64; ++co) ga[co ^ sw] = (_Float16)0.f;
    } else {
        float vin[27];
        #pragma unroll
        for (int ci = 0; ci < 3; ++ci)
            #pragma unroll
            for (int ky = 0; ky < 3; ++ky)
                #pragma unroll
                for (int kx = 0; kx < 3; ++kx)
                    vin[ci * 9 + ky * 3 + kx] = inl[ci][py - 1 + ky][px - 1 + kx];
        for (int co = q * 64; co < q * 64 + 64; ++co) {
            float acc = b1[co];
            const float* wp = &lw[co * 27];
            #pragma unroll
            for (int k = 0; k < 27; ++k) acc += vin[k] * wp[k];
            ga[co ^ sw] = (_Float16)fmaxf(acc, 0.f);
        }
    }
}

// ---------------- conv 3x3 256->256 + ReLU, MFMA implicit GEMM, in-place ----------------
__global__ __launch_bounds__(1024, 4) void conv3x3_kernel(_Float16* __restrict__ act,
                                                          const _Float16* __restrict__ pk,
                                                          const float* __restrict__ bias) {
    __shared__ _Float16 lds[PLANE];   // 128 KB
    int n = blockIdx.x, tid = threadIdx.x;
    _Float16* ga = act + (size_t)n * PLANE;
    #pragma unroll
    for (int i = 0; i < 8; ++i)
        *(uint4*)(lds + (i * 1024 + tid) * 8) = *(const uint4*)(ga + (i * 1024 + tid) * 8);
    __syncthreads();

    int lane = tid & 63, wid = tid >> 6;
    int wm = wid >> 2, wn = wid & 3;
    int r = lane & 15, kg = lane >> 4;
    int pp[4];
    #pragma unroll
    for (int i = 0; i < 4; ++i) {
        int mt = wm + i * 4, m = mt * 16 + r;
        if (mt < 13 && m < 196) { int y = m / 14, xx = m - y * 14; pp[i] = (y + 1) * 16 + xx + 1; }
        else pp[i] = 17;
    }
    float bia[4];
    #pragma unroll
    for (int ni = 0; ni < 4; ++ni) bia[ni] = bias[(wn * 4 + ni) * 16 + (lane & 15)];

    floatx4 acc[4][4] = {};
    for (int tap = 0; tap < 9; ++tap) {
        int dy = tap / 3 - 1, dx = tap % 3 - 1;
        int ip[4];
        #pragma unroll
        for (int i = 0; i < 4; ++i) ip[i] = pp[i] + dy * 16 + dx;
        const _Float16* pkt = pk + (size_t)tap * (8 * 16 * 64 * 8);
        #pragma unroll
        for (int ks = 0; ks < 8; ++ks) {
            half8 a[4], b[4];
            #pragma unroll
            for (int i = 0; i < 4; ++i) {
                int chunk = (ks * 4 + kg) ^ (ip[i] & 7);
                a[i] = *(const half8*)(lds + ip[i] * 256 + chunk * 8);
            }
            #pragma unroll
            for (int ni = 0; ni < 4; ++ni)
                b[ni] = *(const half8*)(pkt + (((ks * 16) + wn * 4 + ni) * 64 + lane) * 8);
            #pragma unroll
            for (int i = 0; i < 4; ++i)
                #pragma unroll
                for (int ni = 0; ni < 4; ++ni)
                    acc[i][ni] = __builtin_amdgcn_mfma_f32_16x16x32_f16(a[i], b[ni], acc[i][ni], 0, 0, 0);
        }
    }
    #pragma unroll
    for (int i = 0; i < 4; ++i) {
        int mt = wm + i * 4;
        if (mt >= 13) continue;
        #pragma unroll
        for (int ni = 0; ni < 4; ++ni) {
            int co = (wn * 4 + ni) * 16 + (lane & 15);
            #pragma unroll
            for (int reg = 0; reg < 4; ++reg) {
                int m = mt * 16 + kg * 4 + reg;
                if (m >= 196) continue;
                int y = m / 14, xx = m - y * 14;
                int ppix = (y + 1) * 16 + xx + 1;
                float v = fmaxf(acc[i][ni][reg] + bia[ni], 0.f);
                ga[ppix * 256 + (co ^ ((ppix & 7) << 3))] = (_Float16)v;
            }
        }
    }
}

// ---------------- convT (stride2) + ReLU + 1x1 conv + sigmoid, fused ----------------
__global__ __launch_bounds__(1024, 4) void convt_kernel(const _Float16* __restrict__ act,
                                                        const _Float16* __restrict__ pkT,
                                                        const float* __restrict__ bt,
                                                        const float* __restrict__ w5,
                                                        const float* __restrict__ b5,
                                                        float* __restrict__ out) {
    __shared__ _Float16 lds[PLANE];   // 128 KB
    __shared__ float o3[2352];        // 9.2 KB: [pix][c]
    int n = blockIdx.x, tid = threadIdx.x;
    const _Float16* ga = act + (size_t)n * PLANE;
    #pragma unroll
    for (int i = 0; i < 8; ++i)
        *(uint4*)(lds + (i * 1024 + tid) * 8) = *(const uint4*)(ga + (i * 1024 + tid) * 8);
    for (int i = tid; i < 2352; i += 1024) o3[i] = b5[i % 3];
    __syncthreads();

    int lane = tid & 63, wid = tid >> 6;
    int wm = wid >> 2, wn = wid & 3;
    int r = lane & 15, kg = lane >> 4;
    int pp[4];
    #pragma unroll
    for (int i = 0; i < 4; ++i) {
        int mt = wm + i * 4, m = mt * 16 + r;
        if (mt < 13 && m < 196) { int y = m / 14, xx = m - y * 14; pp[i] = (y + 1) * 16 + xx + 1; }
        else pp[i] = 17;
    }
    float bta[4], w5a[4][3];
    #pragma unroll
    for (int ni = 0; ni < 4; ++ni) {
        int co = (wn * 4 + ni) * 16 + (lane & 15);
        bta[ni] = bt[co];
        #pragma unroll
        for (int c = 0; c < 3; ++c) w5a[ni][c] = w5[c * 256 + co];
    }

    const int ntaps[4] = {1, 2, 2, 4};
    const int taps[4][4] = {{4, 0, 0, 0}, {3, 5, 0, 0}, {1, 7, 0, 0}, {0, 2, 6, 8}};
    const int dys[4][4]  = {{0, 0, 0, 0}, {0, 0, 0, 0}, {0, 1, 0, 0}, {0, 0, 1, 1}};
    const int dxs[4][4]  = {{0, 0, 0, 0}, {0, 1, 0, 0}, {0, 0, 0, 0}, {0, 1, 0, 1}};

    for (int cls = 0; cls < 4; ++cls) {
        int ry = cls >> 1, rx = cls & 1;
        floatx4 acc[4][4] = {};
        for (int tt = 0; tt < ntaps[cls]; ++tt) {
            int tap = taps[cls][tt];
            int doff = dys[cls][tt] * 16 + dxs[cls][tt];
            const _Float16* pkt = pkT + (size_t)tap * (8 * 16 * 64 * 8);
            #pragma unroll
            for (int ks = 0; ks < 8; ++ks) {
                half8 a[4];
                #pragma unroll
                for (int i = 0; i < 4; ++i) {
                    int ipx = pp[i] + doff;
                    int chunk = (ks * 4 + kg) ^ (ipx & 7);
                    a[i] = *(const half8*)(lds + ipx * 256 + chunk * 8);
                }
                #pragma unroll
                for (int nh = 0; nh < 2; ++nh) {         // B staged 2-at-a-time: peak regs under 128
                    half8 b[2];
                    #pragma unroll
                    for (int nj = 0; nj < 2; ++nj)
                        b[nj] = *(const half8*)(pkt + (((ks * 16) + wn * 4 + nh * 2 + nj) * 64 + lane) * 8);
                    #pragma unroll
                    for (int i = 0; i < 4; ++i)
                        #pragma unroll
                        for (int nj = 0; nj < 2; ++nj)
                            acc[i][nh * 2 + nj] = __builtin_amdgcn_mfma_f32_16x16x32_f16(a[i], b[nj], acc[i][nh * 2 + nj], 0, 0, 0);
                }
            }
        }
        // ReLU + 1x1 conv: fold ni in regs, shfl-reduce over the 16 lanes sharing a pixel,
        // single-lane atomic (4-way contention across wn waves only).
        #pragma unroll
        for (int i = 0; i < 4; ++i) {
            int mt = wm + i * 4;
            if (mt >= 13) continue;
            #pragma unroll
            for (int reg = 0; reg < 4; ++reg) {
                int m = mt * 16 + kg * 4 + reg;   // same for all 16 lanes of an xor-group
                float pc0 = 0.f, pc1 = 0.f, pc2 = 0.f;
                #pragma unroll
                for (int ni = 0; ni < 4; ++ni) {
                    float v = fmaxf(acc[i][ni][reg] + bta[ni], 0.f);
                    pc0 += v * w5a[ni][0];
                    pc1 += v * w5a[ni][1];
                    pc2 += v * w5a[ni][2];
                }
                #pragma unroll
                for (int s = 1; s < 16; s <<= 1) {
                    pc0 += __shfl_xor(pc0, s, 64);
                    pc1 += __shfl_xor(pc1, s, 64);
                    pc2 += __shfl_xor(pc2, s, 64);
                }
                if ((lane & 15) == 0 && m < 196) {
                    int y = m / 14, xx = m - y * 14;
                    int pix = (2 * y + ry) * 28 + (2 * xx + rx);
                    atomicAdd(&o3[pix * 3 + 0], pc0);
                    atomicAdd(&o3[pix * 3 + 1], pc1);
                    atomicAdd(&o3[pix * 3 + 2], pc2);
                }
            }
        }
    }
    __syncthreads();
    size_t ob = (size_t)n * 2352;
    for (int i = tid; i < 2352; i += 1024) {
        int pix = i / 3, c = i % 3;
        float v = o3[i];
        out[ob + (size_t)c * 784 + pix] = 1.f / (1.f + __expf(-v));
    }
}

extern "C" void kernel_launch(void* const* d_in, const int* in_sizes, int n_in,
                              void* d_out, int out_size, void* d_ws, size_t ws_size,
                              hipStream_t stream) {
    const float* x  = (const float*)d_in[0];
    const float* w1 = (const float*)d_in[1];
    const float* b1 = (const float*)d_in[2];
    const float* w2 = (const float*)d_in[3];
    const float* b2 = (const float*)d_in[4];
    const float* w3 = (const float*)d_in[5];
    const float* b3 = (const float*)d_in[6];
    const float* w4 = (const float*)d_in[7];
    const float* b4 = (const float*)d_in[8];
    const float* wt = (const float*)d_in[9];
    const float* bt = (const float*)d_in[10];
    const float* w5 = (const float*)d_in[11];
    const float* b5 = (const float*)d_in[12];

    size_t need = ((size_t)1024 * PLANE + 4 * (size_t)PK_ELEMS) * sizeof(_Float16);
    if (ws_size < need) return;  // workspace too small — cannot run

    _Float16* act = (_Float16*)d_ws;
    _Float16* pk  = act + (size_t)1024 * PLANE;

    repack_kernel<<<1152, 256, 0, stream>>>(w2, w3, w4, wt, pk);
    conv1_kernel<<<1024, 1024, 0, stream>>>(x, w1, b1, act);
    conv3x3_kernel<<<1024, 1024, 0, stream>>>(act, pk + 0 * (size_t)PK_ELEMS, b2);
    conv3x3_kernel<<<1024, 1024, 0, stream>>>(act, pk + 1 * (size_t)PK_ELEMS, b3);
    conv3x3_kernel<<<1024, 1024, 0, stream>>>(act, pk + 2 * (size_t)PK_ELEMS, b4);
    convt_kernel<<<1024, 1024, 0, stream>>>(act, pk + 3 * (size_t)PK_ELEMS, bt, w5, b5, (float*)d_out);
}